// Round 2
// baseline (8069.388 us; speedup 1.0000x reference)
//
#include <hip/hip_runtime.h>
#include <stdint.h>

// ---- problem constants ----
constexpr int Bb = 4, Ss = 2048, Dd = 1024;
constexpr int Hh = 16, KVh = 4, HDd = 64;
constexpr int Ee = 8, Ff = 1024;
constexpr int Tt = Bb * Ss;           // 8192 tokens
constexpr float EPSf = 1e-6f;

// ---------------- RMSNorm: one block per token, 256 threads, D=1024 ----------------
__global__ __launch_bounds__(256) void rmsnorm_kernel(const float* __restrict__ x,
                                                      const float* __restrict__ w,
                                                      float* __restrict__ out) {
  int t = blockIdx.x, tid = threadIdx.x;
  __shared__ float red[4];
  const float* xr = x + (size_t)t * Dd;
  float v[4]; float ss = 0.f;
#pragma unroll
  for (int i = 0; i < 4; ++i) { v[i] = xr[tid + 256 * i]; ss += v[i] * v[i]; }
#pragma unroll
  for (int off = 32; off; off >>= 1) ss += __shfl_down(ss, off, 64);
  if ((tid & 63) == 0) red[tid >> 6] = ss;
  __syncthreads();
  float tot = red[0] + red[1] + red[2] + red[3];
  float sc = rsqrtf(tot * (1.f / Dd) + EPSf);
  float* orow = out + (size_t)t * Dd;
#pragma unroll
  for (int i = 0; i < 4; ++i) orow[tid + 256 * i] = v[i] * sc * w[tid + 256 * i];
}

// ---------------- Generic tiled GEMM: C[M,N] = A[M,K] @ B[K,N] (all fp32) ----------------
// MODE 0: C = A@B        MODE 1: C = A@B + resid (same layout as C)
template <int MODE>
__global__ __launch_bounds__(256) void gemm_kernel(const float* __restrict__ A,
                                                   const float* __restrict__ Bw,
                                                   float* __restrict__ C,
                                                   const float* __restrict__ resid,
                                                   int M, int N, int Kd) {
  __shared__ float As[16][64];
  __shared__ float Bs[16][64];
  int tid = threadIdx.x;
  int tx = tid & 15, ty = tid >> 4;
  int m0 = blockIdx.y * 64, n0 = blockIdx.x * 64;
  float acc[4][4] = {};
  int ar = tid >> 2, ac = (tid & 3) * 4;      // A tile loader: row ar (0..63), 4 k-cols
  int br = tid >> 4, bc = (tid & 15) * 4;     // B tile loader: k-row br (0..15), 4 n-cols
  const float* Aload = A + (size_t)(m0 + ar) * Kd + ac;
  const float* Bload = Bw + (size_t)br * N + n0 + bc;
  for (int kt = 0; kt < Kd; kt += 16) {
    float4 av = *(const float4*)(Aload + kt);
    float4 bv = *(const float4*)(Bload + (size_t)kt * N);
    __syncthreads();
    As[ac + 0][ar] = av.x; As[ac + 1][ar] = av.y; As[ac + 2][ar] = av.z; As[ac + 3][ar] = av.w;
    *(float4*)&Bs[br][bc] = bv;
    __syncthreads();
#pragma unroll
    for (int kk = 0; kk < 16; ++kk) {
      float4 a4 = *(const float4*)&As[kk][ty * 4];
      float4 b4 = *(const float4*)&Bs[kk][tx * 4];
      float aa[4] = {a4.x, a4.y, a4.z, a4.w};
      float bb[4] = {b4.x, b4.y, b4.z, b4.w};
#pragma unroll
      for (int i = 0; i < 4; ++i)
#pragma unroll
        for (int j = 0; j < 4; ++j) acc[i][j] += aa[i] * bb[j];
    }
  }
#pragma unroll
  for (int i = 0; i < 4; ++i) {
    int m = m0 + ty * 4 + i;
    size_t rowoff = (size_t)m * N + n0 + tx * 4;
    float* crow = C + rowoff;
#pragma unroll
    for (int j = 0; j < 4; ++j) {
      float vv = acc[i][j];
      if (MODE == 1) vv += resid[rowoff + j];
      crow[j] = vv;
    }
  }
}

// ---------------- Fused SwiGLU up GEMM: he = silu(A@Wg) * (A@Wu) ----------------
__global__ __launch_bounds__(256) void gemm_gateup_kernel(const float* __restrict__ A,
                                                          const float* __restrict__ Bg,
                                                          const float* __restrict__ Bu,
                                                          float* __restrict__ C,
                                                          int M, int N, int Kd) {
  __shared__ float As[16][64];
  __shared__ float Bgs[16][64];
  __shared__ float Bus[16][64];
  int tid = threadIdx.x;
  int tx = tid & 15, ty = tid >> 4;
  int m0 = blockIdx.y * 64, n0 = blockIdx.x * 64;
  float accg[4][4] = {}, accu[4][4] = {};
  int ar = tid >> 2, ac = (tid & 3) * 4;
  int br = tid >> 4, bc = (tid & 15) * 4;
  const float* Aload = A + (size_t)(m0 + ar) * Kd + ac;
  const float* Bgl = Bg + (size_t)br * N + n0 + bc;
  const float* Bul = Bu + (size_t)br * N + n0 + bc;
  for (int kt = 0; kt < Kd; kt += 16) {
    float4 av = *(const float4*)(Aload + kt);
    float4 gv = *(const float4*)(Bgl + (size_t)kt * N);
    float4 uv = *(const float4*)(Bul + (size_t)kt * N);
    __syncthreads();
    As[ac + 0][ar] = av.x; As[ac + 1][ar] = av.y; As[ac + 2][ar] = av.z; As[ac + 3][ar] = av.w;
    *(float4*)&Bgs[br][bc] = gv;
    *(float4*)&Bus[br][bc] = uv;
    __syncthreads();
#pragma unroll
    for (int kk = 0; kk < 16; ++kk) {
      float4 a4 = *(const float4*)&As[kk][ty * 4];
      float4 g4 = *(const float4*)&Bgs[kk][tx * 4];
      float4 u4 = *(const float4*)&Bus[kk][tx * 4];
      float aa[4] = {a4.x, a4.y, a4.z, a4.w};
      float gg[4] = {g4.x, g4.y, g4.z, g4.w};
      float uu[4] = {u4.x, u4.y, u4.z, u4.w};
#pragma unroll
      for (int i = 0; i < 4; ++i)
#pragma unroll
        for (int j = 0; j < 4; ++j) {
          accg[i][j] += aa[i] * gg[j];
          accu[i][j] += aa[i] * uu[j];
        }
    }
  }
#pragma unroll
  for (int i = 0; i < 4; ++i) {
    int m = m0 + ty * 4 + i;
    float* crow = C + (size_t)m * N + n0 + tx * 4;
#pragma unroll
    for (int j = 0; j < 4; ++j) {
      float g = accg[i][j];
      float sig = 1.f / (1.f + __expf(-g));
      crow[j] = g * sig * accu[i][j];
    }
  }
}

// ---------------- Down GEMM with per-row gate scale, accumulating: C += g_row * (A@B) ----------------
__global__ __launch_bounds__(256) void gemm_down_kernel(const float* __restrict__ A,
                                                        const float* __restrict__ Bw,
                                                        float* __restrict__ C,
                                                        const float* __restrict__ gates,
                                                        int e, int M, int N, int Kd) {
  __shared__ float As[16][64];
  __shared__ float Bs[16][64];
  int tid = threadIdx.x;
  int tx = tid & 15, ty = tid >> 4;
  int m0 = blockIdx.y * 64, n0 = blockIdx.x * 64;
  float acc[4][4] = {};
  int ar = tid >> 2, ac = (tid & 3) * 4;
  int br = tid >> 4, bc = (tid & 15) * 4;
  const float* Aload = A + (size_t)(m0 + ar) * Kd + ac;
  const float* Bload = Bw + (size_t)br * N + n0 + bc;
  for (int kt = 0; kt < Kd; kt += 16) {
    float4 av = *(const float4*)(Aload + kt);
    float4 bv = *(const float4*)(Bload + (size_t)kt * N);
    __syncthreads();
    As[ac + 0][ar] = av.x; As[ac + 1][ar] = av.y; As[ac + 2][ar] = av.z; As[ac + 3][ar] = av.w;
    *(float4*)&Bs[br][bc] = bv;
    __syncthreads();
#pragma unroll
    for (int kk = 0; kk < 16; ++kk) {
      float4 a4 = *(const float4*)&As[kk][ty * 4];
      float4 b4 = *(const float4*)&Bs[kk][tx * 4];
      float aa[4] = {a4.x, a4.y, a4.z, a4.w};
      float bb[4] = {b4.x, b4.y, b4.z, b4.w};
#pragma unroll
      for (int i = 0; i < 4; ++i)
#pragma unroll
        for (int j = 0; j < 4; ++j) acc[i][j] += aa[i] * bb[j];
    }
  }
#pragma unroll
  for (int i = 0; i < 4; ++i) {
    int m = m0 + ty * 4 + i;
    float g = gates[(size_t)m * Ee + e];
    float* crow = C + (size_t)m * N + n0 + tx * 4;
#pragma unroll
    for (int j = 0; j < 4; ++j) crow[j] += g * acc[i][j];
  }
}

// ---------------- RoPE on q (in place) ----------------
__global__ __launch_bounds__(256) void rope_q_kernel(float* __restrict__ q,
                                                     const float* __restrict__ cosb,
                                                     const float* __restrict__ sinb) {
  int idx = blockIdx.x * 256 + threadIdx.x;  // Tt*H*32
  int d = idx & 31;
  int hh = (idx >> 5) & (Hh - 1);
  int t = idx >> 9;
  int s = t & (Ss - 1);
  float c = cosb[s * HDd + d], sn = sinb[s * HDd + d];
  float* qp = q + (size_t)t * (Hh * HDd) + hh * HDd;
  float a = qp[d], b = qp[d + 32];
  qp[d] = a * c - b * sn;
  qp[d + 32] = b * c + a * sn;
}

// ---------------- RoPE on k (in place) + emit k,v outputs ----------------
__global__ __launch_bounds__(256) void ropek_kv_kernel(float* __restrict__ kf,
                                                       const float* __restrict__ vf,
                                                       const float* __restrict__ cosb,
                                                       const float* __restrict__ sinb,
                                                       float* __restrict__ outk,
                                                       float* __restrict__ outv) {
  int idx = blockIdx.x * 256 + threadIdx.x;  // Tt*KV*32
  int d = idx & 31;
  int kv = (idx >> 5) & (KVh - 1);
  int t = idx >> 7;
  int s = t & (Ss - 1);
  float c = cosb[s * HDd + d], sn = sinb[s * HDd + d];
  size_t base = (size_t)t * (KVh * HDd) + kv * HDd;
  float a = kf[base + d], b = kf[base + d + 32];
  float r1 = a * c - b * sn, r2 = b * c + a * sn;
  kf[base + d] = r1; kf[base + d + 32] = r2;
  outk[base + d] = r1; outk[base + d + 32] = r2;
  outv[base + d] = vf[base + d]; outv[base + d + 32] = vf[base + d + 32];
}

// ---------------- Flash attention: 1 thread = 1 query row; block = 256 rows of one (b,h) ----------------
__global__ __launch_bounds__(256) void flash_kernel(const float* __restrict__ q,
                                                    const float* __restrict__ kf,
                                                    const float* __restrict__ vf,
                                                    float* __restrict__ o) {
  __shared__ float Kt[64][64];
  __shared__ float Vt[64][64];
  int tid = threadIdx.x;
  int qt = blockIdx.x & 7;          // 8 q-tiles of 256 per sequence
  int bh = blockIdx.x >> 3;         // b*H + h
  int b = bh >> 4, hh = bh & 15;
  int iq = qt * 256 + tid;
  size_t t = (size_t)b * Ss + iq;
  const float* qp = q + t * (Hh * HDd) + hh * HDd;
  int kvh = hh >> 2;                // H/KV = 4
  const float* Kbase = kf + (size_t)b * Ss * (KVh * HDd) + kvh * HDd;
  const float* Vbase = vf + (size_t)b * Ss * (KVh * HDd) + kvh * HDd;
  float qr[64], oacc[64];
#pragma unroll
  for (int c = 0; c < 16; ++c) {
    float4 qv = *(const float4*)(qp + c * 4);
    qr[c * 4 + 0] = qv.x * 0.125f; qr[c * 4 + 1] = qv.y * 0.125f;
    qr[c * 4 + 2] = qv.z * 0.125f; qr[c * 4 + 3] = qv.w * 0.125f;
  }
#pragma unroll
  for (int i = 0; i < 64; ++i) oacc[i] = 0.f;
  float m = -1e30f, l = 0.f;
  int kmax = qt * 256 + 256;
  int lr = tid >> 2, lc = (tid & 3) * 16;
  for (int j0 = 0; j0 < kmax; j0 += 64) {
    __syncthreads();
    const float* krow = Kbase + (size_t)(j0 + lr) * (KVh * HDd) + lc;
    const float* vrow = Vbase + (size_t)(j0 + lr) * (KVh * HDd) + lc;
#pragma unroll
    for (int u = 0; u < 4; ++u) {
      *(float4*)&Kt[lr][lc + u * 4] = *(const float4*)(krow + u * 4);
      *(float4*)&Vt[lr][lc + u * 4] = *(const float4*)(vrow + u * 4);
    }
    __syncthreads();
    int jend = iq - j0 + 1; if (jend > 64) jend = 64;
    for (int j = 0; j < jend; ++j) {
      const float4* k4 = (const float4*)Kt[j];
      float s = 0.f;
#pragma unroll
      for (int c = 0; c < 16; ++c) {
        float4 kk = k4[c];
        s += qr[c * 4 + 0] * kk.x + qr[c * 4 + 1] * kk.y + qr[c * 4 + 2] * kk.z + qr[c * 4 + 3] * kk.w;
      }
      float mn = fmaxf(m, s);
      float alpha = __expf(m - mn);
      float p = __expf(s - mn);
      l = l * alpha + p;
      m = mn;
      const float4* v4 = (const float4*)Vt[j];
#pragma unroll
      for (int c = 0; c < 16; ++c) {
        float4 vv = v4[c];
        oacc[c * 4 + 0] = oacc[c * 4 + 0] * alpha + p * vv.x;
        oacc[c * 4 + 1] = oacc[c * 4 + 1] * alpha + p * vv.y;
        oacc[c * 4 + 2] = oacc[c * 4 + 2] * alpha + p * vv.z;
        oacc[c * 4 + 3] = oacc[c * 4 + 3] * alpha + p * vv.w;
      }
    }
  }
  float inv = 1.f / l;
  float* op = o + t * (Hh * HDd) + hh * HDd;
#pragma unroll
  for (int i = 0; i < 64; ++i) op[i] = oacc[i] * inv;
}

// ---------------- Router: logits = y @ rw (D x 8), top-2 softmax -> gates[T][8] ----------------
__global__ __launch_bounds__(64) void router_kernel(const float* __restrict__ y,
                                                    const float* __restrict__ rw,
                                                    float* __restrict__ gates) {
  int t = blockIdx.x, lane = threadIdx.x;
  const float* yr = y + (size_t)t * Dd;
  float acc[8] = {};
  for (int i = lane; i < Dd; i += 64) {
    float yv = yr[i];
    float4 w0 = *(const float4*)(rw + (size_t)i * 8);
    float4 w1 = *(const float4*)(rw + (size_t)i * 8 + 4);
    acc[0] += yv * w0.x; acc[1] += yv * w0.y;
    acc[2] += yv * w0.z; acc[3] += yv * w0.w;
    acc[4] += yv * w1.x; acc[5] += yv * w1.y;
    acc[6] += yv * w1.z; acc[7] += yv * w1.w;
  }
#pragma unroll
  for (int off = 32; off; off >>= 1)
#pragma unroll
    for (int e = 0; e < 8; ++e) acc[e] += __shfl_down(acc[e], off, 64);
  if (lane == 0) {
    int i0 = 0; float v0 = acc[0];
#pragma unroll
    for (int e = 1; e < 8; ++e) if (acc[e] > v0) { v0 = acc[e]; i0 = e; }
    int i1 = -1; float v1 = -3.4e38f;
#pragma unroll
    for (int e = 0; e < 8; ++e) if (e != i0 && acc[e] > v1) { v1 = acc[e]; i1 = e; }
    float e1 = __expf(v1 - v0);
    float inv = 1.f / (1.f + e1);
    float* gr = gates + (size_t)t * 8;
#pragma unroll
    for (int e = 0; e < 8; ++e) gr[e] = (e == i0) ? inv : ((e == i1) ? e1 * inv : 0.f);
  }
}

extern "C" void kernel_launch(void* const* d_in, const int* in_sizes, int n_in,
                              void* d_out, int out_size, void* d_ws, size_t ws_size,
                              hipStream_t stream) {
  const float* x      = (const float*)d_in[0];
  const float* cosb   = (const float*)d_in[1];
  const float* sinb   = (const float*)d_in[2];
  // d_in[3] = mask (causal tril) — hard-coded in flash kernel
  const float* w_attn = (const float*)d_in[4];
  const float* w_moe  = (const float*)d_in[5];
  const float* Wq = (const float*)d_in[6];
  const float* Wk = (const float*)d_in[7];
  const float* Wv = (const float*)d_in[8];
  const float* Wo = (const float*)d_in[9];
  const float* Wr = (const float*)d_in[10];
  const float* Wg = (const float*)d_in[11];
  const float* Wu = (const float*)d_in[12];
  const float* Wd = (const float*)d_in[13];
  float* out  = (float*)d_out;
  float* outk = out + (size_t)Tt * Dd;                 // 8,388,608
  float* outv = outk + (size_t)Tt * KVh * HDd;         // +2,097,152
  float* acc  = out;                                   // MoE accumulates directly into d_out

  float* ws = (float*)d_ws;
  // region reuse: xn -> o(attn) ; q -> y ; h -> he ; gates over dead kf
  float* xn    = ws;                       // 8,388,608 f
  float* q     = ws + 8388608;             // 8,388,608 f
  float* kf    = ws + 16777216;            // 2,097,152 f
  float* vf    = ws + 18874368;            // 2,097,152 f
  float* h     = ws + 20971520;            // 8,388,608 f  (total 29,360,128 f = 112 MB)
  float* o_    = xn;
  float* y     = q;
  float* he    = h;
  float* gates = kf;                       // 65,536 f, kf dead after flash

  // 1. xn = rmsnorm(x, w_attn)
  rmsnorm_kernel<<<Tt, 256, 0, stream>>>(x, w_attn, xn);
  // 2. q/k/v projections
  gemm_kernel<0><<<dim3(Dd / 64, Tt / 64), 256, 0, stream>>>(xn, Wq, q, nullptr, Tt, Dd, Dd);
  gemm_kernel<0><<<dim3((KVh * HDd) / 64, Tt / 64), 256, 0, stream>>>(xn, Wk, kf, nullptr, Tt, KVh * HDd, Dd);
  gemm_kernel<0><<<dim3((KVh * HDd) / 64, Tt / 64), 256, 0, stream>>>(xn, Wv, vf, nullptr, Tt, KVh * HDd, Dd);
  // 3. RoPE; emit k,v outputs
  rope_q_kernel<<<(Tt * Hh * 32) / 256, 256, 0, stream>>>(q, cosb, sinb);
  ropek_kv_kernel<<<(Tt * KVh * 32) / 256, 256, 0, stream>>>(kf, vf, cosb, sinb, outk, outv);
  // 4. causal GQA attention -> o (reuses xn region)
  flash_kernel<<<Bb * Hh * (Ss / 256), 256, 0, stream>>>(q, kf, vf, o_);
  // 5. h = o @ Wo + x
  gemm_kernel<1><<<dim3(Dd / 64, Tt / 64), 256, 0, stream>>>(o_, Wo, h, x, Tt, Dd, Dd);
  // 6. y = rmsnorm(h, w_moe)  (reuses q region)
  rmsnorm_kernel<<<Tt, 256, 0, stream>>>(h, w_moe, y);
  // 7. router gates
  router_kernel<<<Tt, 64, 0, stream>>>(y, Wr, gates);
  // 8. acc(=d_out) = h, then MoE accumulates onto it
  hipMemcpyAsync(acc, h, (size_t)Tt * Dd * sizeof(float), hipMemcpyDeviceToDevice, stream);
  // 9. dense MoE over all experts (gates are 0 for unrouted tokens)
  for (int e = 0; e < Ee; ++e) {
    const float* Wge = Wg + (size_t)e * Dd * Ff;
    const float* Wue = Wu + (size_t)e * Dd * Ff;
    const float* Wde = Wd + (size_t)e * Ff * Dd;
    gemm_gateup_kernel<<<dim3(Ff / 64, Tt / 64), 256, 0, stream>>>(y, Wge, Wue, he, Tt, Ff, Dd);
    gemm_down_kernel<<<dim3(Dd / 64, Tt / 64), 256, 0, stream>>>(he, Wde, acc, gates, e, Tt, Dd, Ff);
  }
}

// Round 4
// 3824.059 us; speedup vs baseline: 2.1102x; 2.1102x over previous
//
#include <hip/hip_runtime.h>
#include <stdint.h>

// ---- problem constants ----
constexpr int Bb = 4, Ss = 2048, Dd = 1024;
constexpr int Hh = 16, KVh = 4, HDd = 64;
constexpr int Ee = 8, Ff = 1024;
constexpr int Tt = Bb * Ss;           // 8192 tokens
constexpr float EPSf = 1e-6f;

typedef unsigned short u16;
typedef __attribute__((ext_vector_type(8))) short short8;   // 8 bf16 (4 VGPRs)
typedef __attribute__((ext_vector_type(4))) float f32x4;    // 4 fp32 acc

__device__ __forceinline__ float bf2f(u16 u) {
  union { unsigned int i; float f; } x; x.i = ((unsigned int)u) << 16; return x.f;
}
__device__ __forceinline__ u16 f2bf(float f) {
  union { float f; unsigned int i; } x; x.f = f;
  unsigned int r = x.i + 0x7fffu + ((x.i >> 16) & 1u);
  return (u16)(r >> 16);
}
__device__ __forceinline__ void storef(float* p, float v) { *p = v; }
__device__ __forceinline__ void storef(u16* p, float v) { *p = f2bf(v); }

// ---------------- fp32 [1024][N] -> bf16 [N][1024] transpose-convert ----------------
__global__ __launch_bounds__(256) void transpose_kernel(const float* __restrict__ W,
                                                        u16* __restrict__ WT, int N) {
  __shared__ float tile[64][65];
  int n0 = blockIdx.x * 64, k0 = blockIdx.y * 64;
  int tid = threadIdx.x, r = tid >> 6, c = tid & 63;
#pragma unroll
  for (int p = 0; p < 16; ++p)
    tile[p * 4 + r][c] = W[(size_t)(k0 + p * 4 + r) * N + n0 + c];
  __syncthreads();
#pragma unroll
  for (int p = 0; p < 16; ++p)
    WT[(size_t)(n0 + p * 4 + r) * 1024 + k0 + c] = f2bf(tile[c][p * 4 + r]);
}

// ---------------- RMSNorm: fp32 in -> fp32 or bf16 out ----------------
template <typename TOUT>
__global__ __launch_bounds__(256) void rmsnorm_kernel(const float* __restrict__ x,
                                                      const float* __restrict__ w,
                                                      TOUT* __restrict__ out) {
  int t = blockIdx.x, tid = threadIdx.x;
  __shared__ float red[4];
  const float* xr = x + (size_t)t * Dd;
  float v[4]; float ss = 0.f;
#pragma unroll
  for (int i = 0; i < 4; ++i) { v[i] = xr[tid + 256 * i]; ss += v[i] * v[i]; }
#pragma unroll
  for (int off = 32; off; off >>= 1) ss += __shfl_down(ss, off, 64);
  if ((tid & 63) == 0) red[tid >> 6] = ss;
  __syncthreads();
  float tot = red[0] + red[1] + red[2] + red[3];
  float sc = rsqrtf(tot * (1.f / Dd) + EPSf);
  TOUT* orow = out + (size_t)t * Dd;
#pragma unroll
  for (int i = 0; i < 4; ++i) storef(orow + tid + 256 * i, v[i] * sc * w[tid + 256 * i]);
}

// ---------------- fp32 tiled GEMM (attention path — router-precision-critical) ----------------
// MODE 0: C = A@B        MODE 1: C = A@B + resid
template <int MODE>
__global__ __launch_bounds__(256) void gemm_kernel(const float* __restrict__ A,
                                                   const float* __restrict__ Bw,
                                                   float* __restrict__ C,
                                                   const float* __restrict__ resid,
                                                   int M, int N, int Kd) {
  __shared__ float As[16][64];
  __shared__ float Bs[16][64];
  int tid = threadIdx.x;
  int tx = tid & 15, ty = tid >> 4;
  int m0 = blockIdx.y * 64, n0 = blockIdx.x * 64;
  float acc[4][4] = {};
  int ar = tid >> 2, ac = (tid & 3) * 4;
  int br = tid >> 4, bc = (tid & 15) * 4;
  const float* Aload = A + (size_t)(m0 + ar) * Kd + ac;
  const float* Bload = Bw + (size_t)br * N + n0 + bc;
  for (int kt = 0; kt < Kd; kt += 16) {
    float4 av = *(const float4*)(Aload + kt);
    float4 bv = *(const float4*)(Bload + (size_t)kt * N);
    __syncthreads();
    As[ac + 0][ar] = av.x; As[ac + 1][ar] = av.y; As[ac + 2][ar] = av.z; As[ac + 3][ar] = av.w;
    *(float4*)&Bs[br][bc] = bv;
    __syncthreads();
#pragma unroll
    for (int kk = 0; kk < 16; ++kk) {
      float4 a4 = *(const float4*)&As[kk][ty * 4];
      float4 b4 = *(const float4*)&Bs[kk][tx * 4];
      float aa[4] = {a4.x, a4.y, a4.z, a4.w};
      float bb[4] = {b4.x, b4.y, b4.z, b4.w};
#pragma unroll
      for (int i = 0; i < 4; ++i)
#pragma unroll
        for (int j = 0; j < 4; ++j) acc[i][j] += aa[i] * bb[j];
    }
  }
#pragma unroll
  for (int i = 0; i < 4; ++i) {
    int m = m0 + ty * 4 + i;
    size_t rowoff = (size_t)m * N + n0 + tx * 4;
    float* crow = C + rowoff;
#pragma unroll
    for (int j = 0; j < 4; ++j) {
      float vv = acc[i][j];
      if (MODE == 1) vv += resid[rowoff + j];
      crow[j] = vv;
    }
  }
}

// ---------------- MFMA bf16 GEMM (MoE path): C[M,N] = A[M,K]bf16 @ BT[N,K]bf16 ----------------
// MODE 2: Cb = bf16(C)    MODE 3: Cf += gate[m]*C
template <int MODE>
__global__ __launch_bounds__(256) void mfma_gemm(const u16* __restrict__ A,
                                                 const u16* __restrict__ BT,
                                                 float* __restrict__ Cf,
                                                 u16* __restrict__ Cb,
                                                 const float* __restrict__ gates, int e,
                                                 int N, int K) {
  constexpr int LS = 40;                 // u16 row stride (32 + 8 pad)
  __shared__ u16 As[128 * LS];
  __shared__ u16 Bs[128 * LS];
  int tid = threadIdx.x;
  int m0 = blockIdx.y * 128, n0 = blockIdx.x * 128;
  int lane = tid & 63, w = tid >> 6;
  int wm = (w & 1) * 64, wn = (w >> 1) * 64;
  f32x4 acc[4][4];
#pragma unroll
  for (int i = 0; i < 4; ++i)
#pragma unroll
    for (int j = 0; j < 4; ++j) acc[i][j] = (f32x4){0.f, 0.f, 0.f, 0.f};

  int row = tid >> 2, col8 = (tid & 3) * 8;
  int row1 = row + 64;
  const u16* gA0 = A + (size_t)(m0 + row) * K + col8;
  const u16* gA1 = A + (size_t)(m0 + row1) * K + col8;
  const u16* gB0 = BT + (size_t)(n0 + row) * K + col8;
  const u16* gB1 = BT + (size_t)(n0 + row1) * K + col8;
  int lo0 = row * LS + col8, lo1 = row1 * LS + col8;
  int afo[4], bfo[4];
#pragma unroll
  for (int i = 0; i < 4; ++i) {
    afo[i] = (wm + i * 16 + (lane & 15)) * LS + (lane >> 4) * 8;
    bfo[i] = (wn + i * 16 + (lane & 15)) * LS + (lane >> 4) * 8;
  }

  for (int kt = 0; kt < K; kt += 32) {
    short8 va0 = *(const short8*)(gA0 + kt);
    short8 va1 = *(const short8*)(gA1 + kt);
    short8 vb0 = *(const short8*)(gB0 + kt);
    short8 vb1 = *(const short8*)(gB1 + kt);
    __syncthreads();
    *(short8*)&As[lo0] = va0;
    *(short8*)&As[lo1] = va1;
    *(short8*)&Bs[lo0] = vb0;
    *(short8*)&Bs[lo1] = vb1;
    __syncthreads();
    short8 af[4], bfr[4];
#pragma unroll
    for (int i = 0; i < 4; ++i) af[i] = *(const short8*)&As[afo[i]];
#pragma unroll
    for (int j = 0; j < 4; ++j) bfr[j] = *(const short8*)&Bs[bfo[j]];
#pragma unroll
    for (int i = 0; i < 4; ++i)
#pragma unroll
      for (int j = 0; j < 4; ++j)
        acc[i][j] = __builtin_amdgcn_mfma_f32_16x16x32_bf16(af[i], bfr[j], acc[i][j], 0, 0, 0);
  }

  int r0 = (lane >> 4) * 4, cc = lane & 15;   // C/D: row=(lane>>4)*4+reg, col=lane&15
#pragma unroll
  for (int i = 0; i < 4; ++i) {
#pragma unroll
    for (int r = 0; r < 4; ++r) {
      int m = m0 + wm + i * 16 + r0 + r;
      float g = 0.f;
      if (MODE == 3) g = gates[(size_t)m * Ee + e];
#pragma unroll
      for (int j = 0; j < 4; ++j) {
        int n = n0 + wn + j * 16 + cc;
        size_t off = (size_t)m * N + n;
        float v = acc[i][j][r];
        if (MODE == 2) Cb[off] = f2bf(v);
        else if (MODE == 3) Cf[off] += g * v;
      }
    }
  }
}

// ---------------- RoPE on q (fp32, in place, stride H*HD) ----------------
__global__ __launch_bounds__(256) void rope_q_kernel(float* __restrict__ q,
                                                     const float* __restrict__ cosb,
                                                     const float* __restrict__ sinb) {
  int idx = blockIdx.x * 256 + threadIdx.x;  // Tt*H*32
  int d = idx & 31;
  int hh = (idx >> 5) & (Hh - 1);
  int t = idx >> 9;
  int s = t & (Ss - 1);
  float c = cosb[s * HDd + d], sn = sinb[s * HDd + d];
  float* qp = q + (size_t)t * (Hh * HDd) + hh * HDd;
  float a = qp[d], b = qp[d + 32];
  qp[d] = a * c - b * sn;
  qp[d + 32] = b * c + a * sn;
}

// ---------------- RoPE on k (in place) + emit fp32 k,v outputs ----------------
__global__ __launch_bounds__(256) void ropek_kv_kernel(float* __restrict__ kf,
                                                       const float* __restrict__ vf,
                                                       const float* __restrict__ cosb,
                                                       const float* __restrict__ sinb,
                                                       float* __restrict__ outk,
                                                       float* __restrict__ outv) {
  int idx = blockIdx.x * 256 + threadIdx.x;  // Tt*KV*32
  int d = idx & 31;
  int kv = (idx >> 5) & (KVh - 1);
  int t = idx >> 7;
  int s = t & (Ss - 1);
  float c = cosb[s * HDd + d], sn = sinb[s * HDd + d];
  size_t base = (size_t)t * (KVh * HDd) + kv * HDd;
  float a = kf[base + d], b = kf[base + d + 32];
  float r1 = a * c - b * sn, r2 = b * c + a * sn;
  kf[base + d] = r1; kf[base + d + 32] = r2;
  outk[base + d] = r1; outk[base + d + 32] = r2;
  outv[base + d] = vf[base + d]; outv[base + d + 32] = vf[base + d + 32];
}

// ---------------- Flash attention, fp32, chunked rescale (32-key sub-chunks) ----------------
__global__ __launch_bounds__(256, 2) void flash_kernel(const float* __restrict__ q,
                                                       const float* __restrict__ kf,
                                                       const float* __restrict__ vf,
                                                       float* __restrict__ o) {
  __shared__ float Kt[64][64];
  __shared__ float Vt[64][64];
  int tid = threadIdx.x;
  int qt = blockIdx.x & 7;          // 8 q-tiles of 256 per sequence
  int bh = blockIdx.x >> 3;         // b*H + h
  int b = bh >> 4, hh = bh & 15;
  int iq = qt * 256 + tid;
  size_t t = (size_t)b * Ss + iq;
  const float* qp = q + t * (Hh * HDd) + hh * HDd;
  int kvh = hh >> 2;                // H/KV = 4
  const float* Kbase = kf + (size_t)b * Ss * (KVh * HDd) + kvh * HDd;
  const float* Vbase = vf + (size_t)b * Ss * (KVh * HDd) + kvh * HDd;
  float qr[64], oacc[64];
#pragma unroll
  for (int c = 0; c < 16; ++c) {
    float4 qv = *(const float4*)(qp + c * 4);
    qr[c * 4 + 0] = qv.x * 0.125f; qr[c * 4 + 1] = qv.y * 0.125f;
    qr[c * 4 + 2] = qv.z * 0.125f; qr[c * 4 + 3] = qv.w * 0.125f;
  }
#pragma unroll
  for (int i = 0; i < 64; ++i) oacc[i] = 0.f;
  float m = -1e30f, l = 0.f;
  int kmax = qt * 256 + 256;
  int lr = tid >> 2, lc = (tid & 3) * 16;
  for (int j0 = 0; j0 < kmax; j0 += 64) {
    __syncthreads();
    const float* krow = Kbase + (size_t)(j0 + lr) * (KVh * HDd) + lc;
    const float* vrow = Vbase + (size_t)(j0 + lr) * (KVh * HDd) + lc;
#pragma unroll
    for (int u = 0; u < 4; ++u) {
      *(float4*)&Kt[lr][lc + u * 4] = *(const float4*)(krow + u * 4);
      *(float4*)&Vt[lr][lc + u * 4] = *(const float4*)(vrow + u * 4);
    }
    __syncthreads();
    int jend = iq - j0 + 1;                    // ≤0: tile fully masked for this thread
    if (jend > 0) {                            // exec-masked; dead waves skip via execz
      if (jend > 64) jend = 64;
#pragma unroll 1
      for (int sub = 0; sub < 64; sub += 32) {
        if (jend > sub) {
          float sc[32];
          // 32 independent dot products (ILP), causal mask folded in
#pragma unroll
          for (int j = 0; j < 32; ++j) {
            const float4* k4 = (const float4*)Kt[sub + j];
            float s0 = 0.f, s1 = 0.f, s2 = 0.f, s3 = 0.f;
#pragma unroll
            for (int c = 0; c < 4; ++c) {
              float4 ka = k4[c];
              float4 kb = k4[c + 4];
              float4 kc = k4[c + 8];
              float4 kd = k4[c + 12];
              s0 += qr[c * 4 + 0] * ka.x + qr[c * 4 + 1] * ka.y + qr[c * 4 + 2] * ka.z + qr[c * 4 + 3] * ka.w;
              s1 += qr[c * 4 + 16] * kb.x + qr[c * 4 + 17] * kb.y + qr[c * 4 + 18] * kb.z + qr[c * 4 + 19] * kb.w;
              s2 += qr[c * 4 + 32] * kc.x + qr[c * 4 + 33] * kc.y + qr[c * 4 + 34] * kc.z + qr[c * 4 + 35] * kc.w;
              s3 += qr[c * 4 + 48] * kd.x + qr[c * 4 + 49] * kd.y + qr[c * 4 + 50] * kd.z + qr[c * 4 + 51] * kd.w;
            }
            float s = (s0 + s1) + (s2 + s3);
            sc[j] = (sub + j < jend) ? s : -1e30f;
          }
          float cm = -1e30f;
#pragma unroll
          for (int j = 0; j < 32; ++j) cm = fmaxf(cm, sc[j]);
          float mn = fmaxf(m, cm);
          float alpha = __expf(m - mn);
          m = mn;
          float ps = 0.f;
#pragma unroll
          for (int j = 0; j < 32; ++j) { sc[j] = __expf(sc[j] - mn); ps += sc[j]; }
          l = l * alpha + ps;
#pragma unroll
          for (int i = 0; i < 64; ++i) oacc[i] *= alpha;
#pragma unroll
          for (int j = 0; j < 32; ++j) {
            float p = sc[j];
            const float4* v4 = (const float4*)Vt[sub + j];
#pragma unroll
            for (int c = 0; c < 16; ++c) {
              float4 vv = v4[c];
              oacc[c * 4 + 0] += p * vv.x;
              oacc[c * 4 + 1] += p * vv.y;
              oacc[c * 4 + 2] += p * vv.z;
              oacc[c * 4 + 3] += p * vv.w;
            }
          }
        }
      }
    }
  }
  float inv = 1.f / l;
  float* op = o + t * (Hh * HDd) + hh * HDd;
#pragma unroll
  for (int i = 0; i < 64; ++i) op[i] = oacc[i] * inv;
}

// ---------------- Fused router: rmsnorm(h) fp32 -> logits -> top-2 softmax gates ----------------
__global__ __launch_bounds__(64) void router_kernel(const float* __restrict__ h,
                                                    const float* __restrict__ wm,
                                                    const float* __restrict__ rw,
                                                    float* __restrict__ gates) {
  int t = blockIdx.x, lane = threadIdx.x;
  const float* hr = h + (size_t)t * Dd;
  float v[16]; float ss = 0.f;
#pragma unroll
  for (int j = 0; j < 16; ++j) { v[j] = hr[lane + j * 64]; ss += v[j] * v[j]; }
#pragma unroll
  for (int off = 32; off; off >>= 1) ss += __shfl_down(ss, off, 64);
  ss = __shfl(ss, 0, 64);
  float sc = rsqrtf(ss * (1.f / Dd) + EPSf);
  float acc[8] = {};
#pragma unroll
  for (int j = 0; j < 16; ++j) {
    int i = lane + j * 64;
    float yv = v[j] * sc * wm[i];
    float4 w0 = *(const float4*)(rw + (size_t)i * 8);
    float4 w1 = *(const float4*)(rw + (size_t)i * 8 + 4);
    acc[0] += yv * w0.x; acc[1] += yv * w0.y;
    acc[2] += yv * w0.z; acc[3] += yv * w0.w;
    acc[4] += yv * w1.x; acc[5] += yv * w1.y;
    acc[6] += yv * w1.z; acc[7] += yv * w1.w;
  }
#pragma unroll
  for (int off = 32; off; off >>= 1)
#pragma unroll
    for (int e = 0; e < 8; ++e) acc[e] += __shfl_down(acc[e], off, 64);
  if (lane == 0) {
    int i0 = 0; float v0 = acc[0];
#pragma unroll
    for (int e = 1; e < 8; ++e) if (acc[e] > v0) { v0 = acc[e]; i0 = e; }
    int i1 = -1; float v1 = -3.4e38f;
#pragma unroll
    for (int e = 0; e < 8; ++e) if (e != i0 && acc[e] > v1) { v1 = acc[e]; i1 = e; }
    float e1 = __expf(v1 - v0);
    float inv = 1.f / (1.f + e1);
    float* gr = gates + (size_t)t * 8;
#pragma unroll
    for (int e = 0; e < 8; ++e) gr[e] = (e == i0) ? inv : ((e == i1) ? e1 * inv : 0.f);
  }
}

// ---------------- silu(g)*u from fused gu [M][2048] bf16 -> he [M][1024] bf16 ----------------
__global__ __launch_bounds__(256) void silu_mul_kernel(const u16* __restrict__ gu,
                                                       u16* __restrict__ he) {
  size_t idx4 = ((size_t)blockIdx.x * 256 + threadIdx.x) * 4;
  size_t m = idx4 >> 10, f = idx4 & 1023;
  const u16* gp = gu + m * 2048 + f;
  ushort4 gv = *(const ushort4*)gp;
  ushort4 uv = *(const ushort4*)(gp + 1024);
  float g[4] = {bf2f(gv.x), bf2f(gv.y), bf2f(gv.z), bf2f(gv.w)};
  float u[4] = {bf2f(uv.x), bf2f(uv.y), bf2f(uv.z), bf2f(uv.w)};
  ushort4 o;
  o.x = f2bf(g[0] / (1.f + __expf(-g[0])) * u[0]);
  o.y = f2bf(g[1] / (1.f + __expf(-g[1])) * u[1]);
  o.z = f2bf(g[2] / (1.f + __expf(-g[2])) * u[2]);
  o.w = f2bf(g[3] / (1.f + __expf(-g[3])) * u[3]);
  *(ushort4*)(he + m * 1024 + f) = o;
}

extern "C" void kernel_launch(void* const* d_in, const int* in_sizes, int n_in,
                              void* d_out, int out_size, void* d_ws, size_t ws_size,
                              hipStream_t stream) {
  const float* x      = (const float*)d_in[0];
  const float* cosb   = (const float*)d_in[1];
  const float* sinb   = (const float*)d_in[2];
  // d_in[3] = mask — causal, hard-coded in flash
  const float* w_attn = (const float*)d_in[4];
  const float* w_moe  = (const float*)d_in[5];
  const float* Wq = (const float*)d_in[6];
  const float* Wk = (const float*)d_in[7];
  const float* Wv = (const float*)d_in[8];
  const float* Wo = (const float*)d_in[9];
  const float* Wr = (const float*)d_in[10];
  const float* Wg = (const float*)d_in[11];
  const float* Wu = (const float*)d_in[12];
  const float* Wd = (const float*)d_in[13];
  float* out  = (float*)d_out;
  float* outk = out + (size_t)Tt * Dd;
  float* outv = outk + (size_t)Tt * KVh * HDd;

  char* ws8 = (char*)d_ws;                       // 112 MB total (same budget as round 1/2)
  float* xn    = (float*)(ws8);                  // 32 MB : xn -> o -> {y, gates, wbuf}
  float* q     = (float*)(ws8 + 33554432);       // 32 MB : q fp32 -> gu bf16 [T][2048]
  float* kf    = (float*)(ws8 + 67108864);       //  8 MB : kf -> he (he spans kf+vf, 16 MB)
  float* vf    = (float*)(ws8 + 75497472);       //  8 MB
  float* h     = (float*)(ws8 + 83886080);       // 32 MB
  float* o_    = xn;
  u16*   y     = (u16*)(ws8);                    // 16 MB (o dead after Wo gemm)
  float* gates = (float*)(ws8 + 16777216);       // 256 KB
  u16*   wbuf  = (u16*)(ws8 + 17825792);         // 6 MB : WguT [2048][1024] + WdT [1024][1024]
  u16*   WguT  = wbuf;
  u16*   WdT   = wbuf + (size_t)2048 * 1024;
  u16*   gu    = (u16*)q;                        // q dead after flash
  u16*   he    = (u16*)kf;                       // kf/vf dead after flash

  // 1. xn = rmsnorm(x, w_attn)  (fp32 — attention path must stay fp32 for router precision)
  rmsnorm_kernel<float><<<Tt, 256, 0, stream>>>(x, w_attn, xn);
  // 2. q/k/v projections (fp32)
  gemm_kernel<0><<<dim3(16, 128), 256, 0, stream>>>(xn, Wq, q, nullptr, Tt, 1024, 1024);
  gemm_kernel<0><<<dim3(4, 128), 256, 0, stream>>>(xn, Wk, kf, nullptr, Tt, 256, 1024);
  gemm_kernel<0><<<dim3(4, 128), 256, 0, stream>>>(xn, Wv, vf, nullptr, Tt, 256, 1024);
  // 3. RoPE; emit fp32 k,v outputs
  rope_q_kernel<<<(Tt * Hh * 32) / 256, 256, 0, stream>>>(q, cosb, sinb);
  ropek_kv_kernel<<<(Tt * KVh * 32) / 256, 256, 0, stream>>>(kf, vf, cosb, sinb, outk, outv);
  // 4. causal GQA flash attention (fp32, chunked rescale) -> o (xn region)
  flash_kernel<<<Bb * Hh * (Ss / 256), 256, 0, stream>>>(q, kf, vf, o_);
  // 5. h = o @ Wo + x (fp32)
  gemm_kernel<1><<<dim3(16, 128), 256, 0, stream>>>(o_, Wo, h, x, Tt, 1024, 1024);
  // 6. y = rmsnorm(h) -> bf16 (MoE input); fused fp32 router -> gates
  rmsnorm_kernel<u16><<<Tt, 256, 0, stream>>>(h, w_moe, y);
  router_kernel<<<Tt, 64, 0, stream>>>(h, w_moe, Wr, gates);
  // 7. out = h, then MoE accumulates
  hipMemcpyAsync(out, h, (size_t)Tt * Dd * sizeof(float), hipMemcpyDeviceToDevice, stream);
  // 8. dense MoE, bf16 MFMA (gates are 0 for unrouted tokens)
  for (int e = 0; e < Ee; ++e) {
    transpose_kernel<<<dim3(16, 16), 256, 0, stream>>>(Wg + (size_t)e * Dd * Ff, WguT, 1024);
    transpose_kernel<<<dim3(16, 16), 256, 0, stream>>>(Wu + (size_t)e * Dd * Ff, WguT + (size_t)1024 * 1024, 1024);
    transpose_kernel<<<dim3(16, 16), 256, 0, stream>>>(Wd + (size_t)e * Ff * Dd, WdT, 1024);
    mfma_gemm<2><<<dim3(16, 64), 256, 0, stream>>>(y, WguT, nullptr, gu, nullptr, 0, 2048, 1024);
    silu_mul_kernel<<<(Tt * 1024) / 1024, 256, 0, stream>>>(gu, he);
    mfma_gemm<3><<<dim3(8, 64), 256, 0, stream>>>(he, WdT, out, nullptr, gates, e, 1024, 1024);
  }
}

// Round 5
// 3073.720 us; speedup vs baseline: 2.6253x; 1.2441x over previous
//
#include <hip/hip_runtime.h>
#include <stdint.h>

// ---- problem constants ----
constexpr int Bb = 4, Ss = 2048, Dd = 1024;
constexpr int Hh = 16, KVh = 4, HDd = 64;
constexpr int Ee = 8, Ff = 1024;
constexpr int Tt = Bb * Ss;           // 8192 tokens
constexpr float EPSf = 1e-6f;

typedef unsigned short u16;
typedef __attribute__((ext_vector_type(8))) short short8;   // 8 bf16 (4 VGPRs)
typedef __attribute__((ext_vector_type(4))) float f32x4;    // 4 fp32 acc

__device__ __forceinline__ float bf2f(u16 u) {
  union { unsigned int i; float f; } x; x.i = ((unsigned int)u) << 16; return x.f;
}
__device__ __forceinline__ u16 f2bf(float f) {
  union { float f; unsigned int i; } x; x.f = f;
  unsigned int r = x.i + 0x7fffu + ((x.i >> 16) & 1u);
  return (u16)(r >> 16);
}
__device__ __forceinline__ void storef(float* p, float v) { *p = v; }
__device__ __forceinline__ void storef(u16* p, float v) { *p = f2bf(v); }

// ---------------- fp32 [1024][N] -> bf16 [N][1024] transpose-convert ----------------
__global__ __launch_bounds__(256) void transpose_kernel(const float* __restrict__ W,
                                                        u16* __restrict__ WT, int N) {
  __shared__ float tile[64][65];
  int n0 = blockIdx.x * 64, k0 = blockIdx.y * 64;
  int tid = threadIdx.x, r = tid >> 6, c = tid & 63;
#pragma unroll
  for (int p = 0; p < 16; ++p)
    tile[p * 4 + r][c] = W[(size_t)(k0 + p * 4 + r) * N + n0 + c];
  __syncthreads();
#pragma unroll
  for (int p = 0; p < 16; ++p)
    WT[(size_t)(n0 + p * 4 + r) * 1024 + k0 + c] = f2bf(tile[c][p * 4 + r]);
}

// ---------------- RMSNorm: fp32 in -> fp32 or bf16 out ----------------
template <typename TOUT>
__global__ __launch_bounds__(256) void rmsnorm_kernel(const float* __restrict__ x,
                                                      const float* __restrict__ w,
                                                      TOUT* __restrict__ out) {
  int t = blockIdx.x, tid = threadIdx.x;
  __shared__ float red[4];
  const float* xr = x + (size_t)t * Dd;
  float v[4]; float ss = 0.f;
#pragma unroll
  for (int i = 0; i < 4; ++i) { v[i] = xr[tid + 256 * i]; ss += v[i] * v[i]; }
#pragma unroll
  for (int off = 32; off; off >>= 1) ss += __shfl_down(ss, off, 64);
  if ((tid & 63) == 0) red[tid >> 6] = ss;
  __syncthreads();
  float tot = red[0] + red[1] + red[2] + red[3];
  float sc = rsqrtf(tot * (1.f / Dd) + EPSf);
  TOUT* orow = out + (size_t)t * Dd;
#pragma unroll
  for (int i = 0; i < 4; ++i) storef(orow + tid + 256 * i, v[i] * sc * w[tid + 256 * i]);
}

// ---------------- fp32 128x128 tiled GEMM (attention path), 8x8 microtile ----------------
// MODE 0: C = A@B        MODE 1: C = A@B + resid
template <int MODE>
__global__ __launch_bounds__(256) void gemm128(const float* __restrict__ A,
                                               const float* __restrict__ Bw,
                                               float* __restrict__ C,
                                               const float* __restrict__ resid,
                                               int N, int K) {
  __shared__ float As[16][128];   // [k][m]
  __shared__ float Bs[16][128];   // [k][n]
  int tid = threadIdx.x;
  int tx = tid & 15, ty = tid >> 4;
  int m0 = blockIdx.y * 128, n0 = blockIdx.x * 128;
  float acc[8][8] = {};
  int arow = tid >> 1, akc = (tid & 1) * 8;     // A loader: 128 rows, 8 k each
  int bkr = tid >> 4, bnc = (tid & 15) * 8;     // B loader: 16 k-rows, 8 n each
  const float* Ald = A + (size_t)(m0 + arow) * K + akc;
  const float* Bld = Bw + (size_t)bkr * N + n0 + bnc;
  for (int kt = 0; kt < K; kt += 16) {
    float4 a0 = *(const float4*)(Ald + kt);
    float4 a1 = *(const float4*)(Ald + kt + 4);
    float4 b0 = *(const float4*)(Bld + (size_t)kt * N);
    float4 b1 = *(const float4*)(Bld + (size_t)kt * N + 4);
    __syncthreads();
    As[akc + 0][arow] = a0.x; As[akc + 1][arow] = a0.y;
    As[akc + 2][arow] = a0.z; As[akc + 3][arow] = a0.w;
    As[akc + 4][arow] = a1.x; As[akc + 5][arow] = a1.y;
    As[akc + 6][arow] = a1.z; As[akc + 7][arow] = a1.w;
    *(float4*)&Bs[bkr][bnc] = b0;
    *(float4*)&Bs[bkr][bnc + 4] = b1;
    __syncthreads();
#pragma unroll
    for (int kk = 0; kk < 16; ++kk) {
      float4 af0 = *(const float4*)&As[kk][ty * 8];
      float4 af1 = *(const float4*)&As[kk][ty * 8 + 4];
      float4 bf0 = *(const float4*)&Bs[kk][tx * 8];
      float4 bf1 = *(const float4*)&Bs[kk][tx * 8 + 4];
      float aa[8] = {af0.x, af0.y, af0.z, af0.w, af1.x, af1.y, af1.z, af1.w};
      float bb[8] = {bf0.x, bf0.y, bf0.z, bf0.w, bf1.x, bf1.y, bf1.z, bf1.w};
#pragma unroll
      for (int i = 0; i < 8; ++i)
#pragma unroll
        for (int j = 0; j < 8; ++j) acc[i][j] += aa[i] * bb[j];
    }
  }
#pragma unroll
  for (int i = 0; i < 8; ++i) {
    int m = m0 + ty * 8 + i;
    size_t rowoff = (size_t)m * N + n0 + tx * 8;
    float* crow = C + rowoff;
#pragma unroll
    for (int j = 0; j < 8; ++j) {
      float vv = acc[i][j];
      if (MODE == 1) vv += resid[rowoff + j];
      crow[j] = vv;
    }
  }
}

// ---------------- MFMA bf16 GEMM (MoE path): C[M,N] = A[M,K]bf16 @ BT[N,K]bf16 ----------------
// MODE 2: Cb = bf16(C)    MODE 3: Cf += gate[m]*C
template <int MODE>
__global__ __launch_bounds__(256) void mfma_gemm(const u16* __restrict__ A,
                                                 const u16* __restrict__ BT,
                                                 float* __restrict__ Cf,
                                                 u16* __restrict__ Cb,
                                                 const float* __restrict__ gates, int e,
                                                 int N, int K) {
  constexpr int LS = 40;                 // u16 row stride (32 + 8 pad)
  __shared__ u16 As[128 * LS];
  __shared__ u16 Bs[128 * LS];
  int tid = threadIdx.x;
  int m0 = blockIdx.y * 128, n0 = blockIdx.x * 128;
  int lane = tid & 63, w = tid >> 6;
  int wm = (w & 1) * 64, wn = (w >> 1) * 64;
  f32x4 acc[4][4];
#pragma unroll
  for (int i = 0; i < 4; ++i)
#pragma unroll
    for (int j = 0; j < 4; ++j) acc[i][j] = (f32x4){0.f, 0.f, 0.f, 0.f};

  int row = tid >> 2, col8 = (tid & 3) * 8;
  int row1 = row + 64;
  const u16* gA0 = A + (size_t)(m0 + row) * K + col8;
  const u16* gA1 = A + (size_t)(m0 + row1) * K + col8;
  const u16* gB0 = BT + (size_t)(n0 + row) * K + col8;
  const u16* gB1 = BT + (size_t)(n0 + row1) * K + col8;
  int lo0 = row * LS + col8, lo1 = row1 * LS + col8;
  int afo[4], bfo[4];
#pragma unroll
  for (int i = 0; i < 4; ++i) {
    afo[i] = (wm + i * 16 + (lane & 15)) * LS + (lane >> 4) * 8;
    bfo[i] = (wn + i * 16 + (lane & 15)) * LS + (lane >> 4) * 8;
  }

  for (int kt = 0; kt < K; kt += 32) {
    short8 va0 = *(const short8*)(gA0 + kt);
    short8 va1 = *(const short8*)(gA1 + kt);
    short8 vb0 = *(const short8*)(gB0 + kt);
    short8 vb1 = *(const short8*)(gB1 + kt);
    __syncthreads();
    *(short8*)&As[lo0] = va0;
    *(short8*)&As[lo1] = va1;
    *(short8*)&Bs[lo0] = vb0;
    *(short8*)&Bs[lo1] = vb1;
    __syncthreads();
    short8 af[4], bfr[4];
#pragma unroll
    for (int i = 0; i < 4; ++i) af[i] = *(const short8*)&As[afo[i]];
#pragma unroll
    for (int j = 0; j < 4; ++j) bfr[j] = *(const short8*)&Bs[bfo[j]];
#pragma unroll
    for (int i = 0; i < 4; ++i)
#pragma unroll
      for (int j = 0; j < 4; ++j)
        acc[i][j] = __builtin_amdgcn_mfma_f32_16x16x32_bf16(af[i], bfr[j], acc[i][j], 0, 0, 0);
  }

  int r0 = (lane >> 4) * 4, cc = lane & 15;   // C/D: row=(lane>>4)*4+reg, col=lane&15
#pragma unroll
  for (int i = 0; i < 4; ++i) {
#pragma unroll
    for (int r = 0; r < 4; ++r) {
      int m = m0 + wm + i * 16 + r0 + r;
      float g = 0.f;
      if (MODE == 3) g = gates[(size_t)m * Ee + e];
#pragma unroll
      for (int j = 0; j < 4; ++j) {
        int n = n0 + wn + j * 16 + cc;
        size_t off = (size_t)m * N + n;
        float v = acc[i][j][r];
        if (MODE == 2) Cb[off] = f2bf(v);
        else if (MODE == 3) Cf[off] += g * v;
      }
    }
  }
}

// ---------------- RoPE on q (fp32, in place, stride H*HD) ----------------
__global__ __launch_bounds__(256) void rope_q_kernel(float* __restrict__ q,
                                                     const float* __restrict__ cosb,
                                                     const float* __restrict__ sinb) {
  int idx = blockIdx.x * 256 + threadIdx.x;  // Tt*H*32
  int d = idx & 31;
  int hh = (idx >> 5) & (Hh - 1);
  int t = idx >> 9;
  int s = t & (Ss - 1);
  float c = cosb[s * HDd + d], sn = sinb[s * HDd + d];
  float* qp = q + (size_t)t * (Hh * HDd) + hh * HDd;
  float a = qp[d], b = qp[d + 32];
  qp[d] = a * c - b * sn;
  qp[d + 32] = b * c + a * sn;
}

// ---------------- RoPE on k (in place) + emit fp32 k,v outputs ----------------
__global__ __launch_bounds__(256) void ropek_kv_kernel(float* __restrict__ kf,
                                                       const float* __restrict__ vf,
                                                       const float* __restrict__ cosb,
                                                       const float* __restrict__ sinb,
                                                       float* __restrict__ outk,
                                                       float* __restrict__ outv) {
  int idx = blockIdx.x * 256 + threadIdx.x;  // Tt*KV*32
  int d = idx & 31;
  int kv = (idx >> 5) & (KVh - 1);
  int t = idx >> 7;
  int s = t & (Ss - 1);
  float c = cosb[s * HDd + d], sn = sinb[s * HDd + d];
  size_t base = (size_t)t * (KVh * HDd) + kv * HDd;
  float a = kf[base + d], b = kf[base + d + 32];
  float r1 = a * c - b * sn, r2 = b * c + a * sn;
  kf[base + d] = r1; kf[base + d + 32] = r2;
  outk[base + d] = r1; outk[base + d + 32] = r2;
  outv[base + d] = vf[base + d]; outv[base + d + 32] = vf[base + d + 32];
}

// ---------------- Flash attention fp32: lane-pair per q-row (32 dims each) ----------------
// block = 256 threads = 128 q-rows of one (b,h); lanes L / L+32 share a q-row.
// No launch_bounds VGPR cap (round-4 spill lesson: FETCH 614 MB was scratch traffic).
__global__ void flash_kernel(const float* __restrict__ q,
                             const float* __restrict__ kf,
                             const float* __restrict__ vf,
                             float* __restrict__ o) {
  __shared__ float Kt[64][64];
  __shared__ float Vt[64][64];
  int tid = threadIdx.x;
  int qt = 15 - (blockIdx.x & 15);      // 16 q-tiles of 128 per sequence, heavy first
  int bh = blockIdx.x >> 4;             // b*H + h
  int b = bh >> 4, hh = bh & 15;
  int wv = tid >> 6, lane = tid & 63;
  int qlocal = wv * 32 + (lane & 31);
  int dimh = lane >> 5;                 // 0: dims 0..31, 1: dims 32..63
  int iq = qt * 128 + qlocal;
  size_t t = (size_t)b * Ss + iq;
  const float* qp = q + t * (Hh * HDd) + hh * HDd + dimh * 32;
  int kvh = hh >> 2;                    // H/KV = 4
  const float* Kbase = kf + (size_t)b * Ss * (KVh * HDd) + kvh * HDd;
  const float* Vbase = vf + (size_t)b * Ss * (KVh * HDd) + kvh * HDd;
  float qr[32], oacc[32];
#pragma unroll
  for (int c = 0; c < 8; ++c) {
    float4 qv = *(const float4*)(qp + c * 4);
    qr[c * 4 + 0] = qv.x * 0.125f; qr[c * 4 + 1] = qv.y * 0.125f;
    qr[c * 4 + 2] = qv.z * 0.125f; qr[c * 4 + 3] = qv.w * 0.125f;
  }
#pragma unroll
  for (int i = 0; i < 32; ++i) oacc[i] = 0.f;
  float m = -1e30f, l = 0.f;
  int kmax = qt * 128 + 128;
  int lr = tid >> 2, lc = (tid & 3) * 16;
  for (int j0 = 0; j0 < kmax; j0 += 64) {
    __syncthreads();
    const float* krow = Kbase + (size_t)(j0 + lr) * (KVh * HDd) + lc;
    const float* vrow = Vbase + (size_t)(j0 + lr) * (KVh * HDd) + lc;
#pragma unroll
    for (int u = 0; u < 4; ++u) {
      *(float4*)&Kt[lr][lc + u * 4] = *(const float4*)(krow + u * 4);
      *(float4*)&Vt[lr][lc + u * 4] = *(const float4*)(vrow + u * 4);
    }
    __syncthreads();
    int jend = iq - j0 + 1;             // valid keys in this tile for this q-row
    if (jend > 64) jend = 64;
#pragma unroll 1
    for (int chunk = 0; chunk < 64; chunk += 16) {
      if (jend > chunk) {               // pair lanes have equal jend -> shuffle-safe
        float sc[16];
#pragma unroll
        for (int j = 0; j < 16; ++j) {
          const float* kr = &Kt[chunk + j][dimh * 32];
          float s = 0.f;
#pragma unroll
          for (int c = 0; c < 8; ++c) {
            float4 kk = *(const float4*)(kr + c * 4);
            s += qr[c * 4 + 0] * kk.x + qr[c * 4 + 1] * kk.y +
                 qr[c * 4 + 2] * kk.z + qr[c * 4 + 3] * kk.w;
          }
          float full = s + __shfl_xor(s, 32);   // combine dim halves
          sc[j] = (chunk + j < jend) ? full : -1e30f;
        }
        float cm = -1e30f;
#pragma unroll
        for (int j = 0; j < 16; ++j) cm = fmaxf(cm, sc[j]);
        float mn = fmaxf(m, cm);
        float alpha = __expf(m - mn);
        m = mn;
        float ps = 0.f;
#pragma unroll
        for (int j = 0; j < 16; ++j) { sc[j] = __expf(sc[j] - mn); ps += sc[j]; }
        l = l * alpha + ps;
#pragma unroll
        for (int i = 0; i < 32; ++i) oacc[i] *= alpha;
#pragma unroll
        for (int j = 0; j < 16; ++j) {
          float p = sc[j];
          const float* vr = &Vt[chunk + j][dimh * 32];
#pragma unroll
          for (int c = 0; c < 8; ++c) {
            float4 vv = *(const float4*)(vr + c * 4);
            oacc[c * 4 + 0] += p * vv.x;
            oacc[c * 4 + 1] += p * vv.y;
            oacc[c * 4 + 2] += p * vv.z;
            oacc[c * 4 + 3] += p * vv.w;
          }
        }
      }
    }
  }
  float inv = 1.f / l;
  float* op = o + t * (Hh * HDd) + hh * HDd + dimh * 32;
#pragma unroll
  for (int i = 0; i < 32; ++i) op[i] = oacc[i] * inv;
}

// ---------------- Fused router: rmsnorm(h) fp32 -> logits -> top-2 softmax gates ----------------
__global__ __launch_bounds__(64) void router_kernel(const float* __restrict__ h,
                                                    const float* __restrict__ wm,
                                                    const float* __restrict__ rw,
                                                    float* __restrict__ gates) {
  int t = blockIdx.x, lane = threadIdx.x;
  const float* hr = h + (size_t)t * Dd;
  float v[16]; float ss = 0.f;
#pragma unroll
  for (int j = 0; j < 16; ++j) { v[j] = hr[lane + j * 64]; ss += v[j] * v[j]; }
#pragma unroll
  for (int off = 32; off; off >>= 1) ss += __shfl_down(ss, off, 64);
  ss = __shfl(ss, 0, 64);
  float sc = rsqrtf(ss * (1.f / Dd) + EPSf);
  float acc[8] = {};
#pragma unroll
  for (int j = 0; j < 16; ++j) {
    int i = lane + j * 64;
    float yv = v[j] * sc * wm[i];
    float4 w0 = *(const float4*)(rw + (size_t)i * 8);
    float4 w1 = *(const float4*)(rw + (size_t)i * 8 + 4);
    acc[0] += yv * w0.x; acc[1] += yv * w0.y;
    acc[2] += yv * w0.z; acc[3] += yv * w0.w;
    acc[4] += yv * w1.x; acc[5] += yv * w1.y;
    acc[6] += yv * w1.z; acc[7] += yv * w1.w;
  }
#pragma unroll
  for (int off = 32; off; off >>= 1)
#pragma unroll
    for (int e = 0; e < 8; ++e) acc[e] += __shfl_down(acc[e], off, 64);
  if (lane == 0) {
    int i0 = 0; float v0 = acc[0];
#pragma unroll
    for (int e = 1; e < 8; ++e) if (acc[e] > v0) { v0 = acc[e]; i0 = e; }
    int i1 = -1; float v1 = -3.4e38f;
#pragma unroll
    for (int e = 0; e < 8; ++e) if (e != i0 && acc[e] > v1) { v1 = acc[e]; i1 = e; }
    float e1 = __expf(v1 - v0);
    float inv = 1.f / (1.f + e1);
    float* gr = gates + (size_t)t * 8;
#pragma unroll
    for (int e = 0; e < 8; ++e) gr[e] = (e == i0) ? inv : ((e == i1) ? e1 * inv : 0.f);
  }
}

// ---------------- silu(g)*u from fused gu [M][2048] bf16 -> he [M][1024] bf16 ----------------
__global__ __launch_bounds__(256) void silu_mul_kernel(const u16* __restrict__ gu,
                                                       u16* __restrict__ he) {
  size_t idx4 = ((size_t)blockIdx.x * 256 + threadIdx.x) * 4;
  size_t m = idx4 >> 10, f = idx4 & 1023;
  const u16* gp = gu + m * 2048 + f;
  ushort4 gv = *(const ushort4*)gp;
  ushort4 uv = *(const ushort4*)(gp + 1024);
  float g[4] = {bf2f(gv.x), bf2f(gv.y), bf2f(gv.z), bf2f(gv.w)};
  float u[4] = {bf2f(uv.x), bf2f(uv.y), bf2f(uv.z), bf2f(uv.w)};
  ushort4 o;
  o.x = f2bf(g[0] / (1.f + __expf(-g[0])) * u[0]);
  o.y = f2bf(g[1] / (1.f + __expf(-g[1])) * u[1]);
  o.z = f2bf(g[2] / (1.f + __expf(-g[2])) * u[2]);
  o.w = f2bf(g[3] / (1.f + __expf(-g[3])) * u[3]);
  *(ushort4*)(he + m * 1024 + f) = o;
}

extern "C" void kernel_launch(void* const* d_in, const int* in_sizes, int n_in,
                              void* d_out, int out_size, void* d_ws, size_t ws_size,
                              hipStream_t stream) {
  const float* x      = (const float*)d_in[0];
  const float* cosb   = (const float*)d_in[1];
  const float* sinb   = (const float*)d_in[2];
  // d_in[3] = mask — causal, hard-coded in flash
  const float* w_attn = (const float*)d_in[4];
  const float* w_moe  = (const float*)d_in[5];
  const float* Wq = (const float*)d_in[6];
  const float* Wk = (const float*)d_in[7];
  const float* Wv = (const float*)d_in[8];
  const float* Wo = (const float*)d_in[9];
  const float* Wr = (const float*)d_in[10];
  const float* Wg = (const float*)d_in[11];
  const float* Wu = (const float*)d_in[12];
  const float* Wd = (const float*)d_in[13];
  float* out  = (float*)d_out;
  float* outk = out + (size_t)Tt * Dd;
  float* outv = outk + (size_t)Tt * KVh * HDd;

  char* ws8 = (char*)d_ws;                       // 112 MB budget
  float* xn    = (float*)(ws8);                  // 32 MB : xn -> o -> {y, gates, wbuf}
  float* q     = (float*)(ws8 + 33554432);       // 32 MB : q fp32 -> gu bf16 [T][2048]
  float* kf    = (float*)(ws8 + 67108864);       //  8 MB : kf -> he (he spans kf+vf)
  float* vf    = (float*)(ws8 + 75497472);       //  8 MB
  float* h     = (float*)(ws8 + 83886080);       // 32 MB
  float* o_    = xn;
  u16*   y     = (u16*)(ws8);                    // 16 MB (o dead after Wo gemm)
  float* gates = (float*)(ws8 + 16777216);       // 256 KB
  u16*   wbuf  = (u16*)(ws8 + 17825792);         // 6 MB : WguT [2048][1024] + WdT [1024][1024]
  u16*   WguT  = wbuf;
  u16*   WdT   = wbuf + (size_t)2048 * 1024;
  u16*   gu    = (u16*)q;                        // q dead after flash
  u16*   he    = (u16*)kf;                       // kf/vf dead after flash

  // 1. xn = rmsnorm(x, w_attn)  (fp32 — attention path stays fp32 for router precision)
  rmsnorm_kernel<float><<<Tt, 256, 0, stream>>>(x, w_attn, xn);
  // 2. q/k/v projections (fp32, 128x128 tile)
  gemm128<0><<<dim3(8, 64), 256, 0, stream>>>(xn, Wq, q, nullptr, 1024, 1024);
  gemm128<0><<<dim3(2, 64), 256, 0, stream>>>(xn, Wk, kf, nullptr, 256, 1024);
  gemm128<0><<<dim3(2, 64), 256, 0, stream>>>(xn, Wv, vf, nullptr, 256, 1024);
  // 3. RoPE; emit fp32 k,v outputs
  rope_q_kernel<<<(Tt * Hh * 32) / 256, 256, 0, stream>>>(q, cosb, sinb);
  ropek_kv_kernel<<<(Tt * KVh * 32) / 256, 256, 0, stream>>>(kf, vf, cosb, sinb, outk, outv);
  // 4. causal GQA flash attention (fp32, lane-pair dim split) -> o (xn region)
  flash_kernel<<<Bb * Hh * (Ss / 128), 256, 0, stream>>>(q, kf, vf, o_);
  // 5. h = o @ Wo + x (fp32)
  gemm128<1><<<dim3(8, 64), 256, 0, stream>>>(o_, Wo, h, x, 1024, 1024);
  // 6. y = rmsnorm(h) -> bf16 (MoE input); fused fp32 router -> gates
  rmsnorm_kernel<u16><<<Tt, 256, 0, stream>>>(h, w_moe, y);
  router_kernel<<<Tt, 64, 0, stream>>>(h, w_moe, Wr, gates);
  // 7. out = h, then MoE accumulates
  hipMemcpyAsync(out, h, (size_t)Tt * Dd * sizeof(float), hipMemcpyDeviceToDevice, stream);
  // 8. dense MoE, bf16 MFMA (gates are 0 for unrouted tokens)
  for (int e = 0; e < Ee; ++e) {
    transpose_kernel<<<dim3(16, 16), 256, 0, stream>>>(Wg + (size_t)e * Dd * Ff, WguT, 1024);
    transpose_kernel<<<dim3(16, 16), 256, 0, stream>>>(Wu + (size_t)e * Dd * Ff, WguT + (size_t)1024 * 1024, 1024);
    transpose_kernel<<<dim3(16, 16), 256, 0, stream>>>(Wd + (size_t)e * Ff * Dd, WdT, 1024);
    mfma_gemm<2><<<dim3(16, 64), 256, 0, stream>>>(y, WguT, nullptr, gu, nullptr, 0, 2048, 1024);
    silu_mul_kernel<<<(Tt * 1024) / 1024, 256, 0, stream>>>(gu, he);
    mfma_gemm<3><<<dim3(8, 64), 256, 0, stream>>>(he, WdT, out, nullptr, gates, e, 1024, 1024);
  }
}